// Round 13
// baseline (1650.814 us; speedup 1.0000x reference)
//
#include <hip/hip_runtime.h>
#include <math.h>

#define T_TOK 8192
#define H_DIM 2048
#define F_DIM 4096
#define E_NUM 8
#define MAXPAIR (T_TOK * 2)
#define MAX_MT 136
#define BM 128
#define BN 128
#define BK 32
#define NCONV 2048   // w2-convert blocks fused into gemm1 dispatch
#define NCONV13 4096 // w1/w3-convert blocks fused into router dispatch

typedef __attribute__((ext_vector_type(4))) float f32x4;
typedef __attribute__((ext_vector_type(8))) short s16x8;
typedef __attribute__((ext_vector_type(8))) __bf16 bf16x8;
typedef __attribute__((ext_vector_type(4))) unsigned short u16x4;

__device__ __forceinline__ unsigned short f2bf(float f) {
  unsigned int u = __float_as_uint(f);
  u += 0x7FFFu + ((u >> 16) & 1u);
  return (unsigned short)(u >> 16);
}

__device__ __forceinline__ s16x8 pack8(f32x4 a, f32x4 b) {
  s16x8 r;
  r[0] = (short)f2bf(a.x); r[1] = (short)f2bf(a.y);
  r[2] = (short)f2bf(a.z); r[3] = (short)f2bf(a.w);
  r[4] = (short)f2bf(b.x); r[5] = (short)f2bf(b.y);
  r[6] = (short)f2bf(b.z); r[7] = (short)f2bf(b.w);
  return r;
}

#define GLD16(gsrc, ldst)                                                      \
  __builtin_amdgcn_global_load_lds(                                            \
      (__attribute__((address_space(1))) void*)(gsrc),                         \
      (__attribute__((address_space(3))) void*)(ldst), 16, 0, 0)

// ---------------------------------------------------------------------------
// Router + fused w1/w3 fp32->bf16 converts (verified round 9)
// ---------------------------------------------------------------------------
__global__ __launch_bounds__(256) void router_conv_kernel(
    const float* __restrict__ x, const float* __restrict__ gw,
    float* __restrict__ logits, unsigned short* __restrict__ xb,
    int* __restrict__ ctrl, int* __restrict__ tIdx, float* __restrict__ tW,
    const float* __restrict__ w1f, unsigned short* __restrict__ w1b,
    const float* __restrict__ w3f, unsigned short* __restrict__ w3b,
    int nconv) {
  int rb = blockIdx.x;  // router block id
  if (nconv) {
    const int bid = blockIdx.x;
    if ((bid % 3) != 2) {
      const int cid = bid - (bid + 1) / 3;           // 0..4095
      const float* src = (cid < 2048) ? w1f : w3f;
      unsigned short* dst = (cid < 2048) ? w1b : w3b;
      const long long base = (long long)(cid & 2047) * 4096;
#pragma unroll
      for (int it = 0; it < 16; ++it) {
        const long long i = base + it * 256 + threadIdx.x;
        f32x4 a = *(const f32x4*)(src + i * 8);
        f32x4 b = *(const f32x4*)(src + i * 8 + 4);
        *(s16x8*)(dst + i * 8) = pack8(a, b);
      }
      return;
    }
    rb = bid / 3;  // 0..2047
  }

  const int wid = threadIdx.x >> 6, lane = threadIdx.x & 63;
  const int t = rb * 4 + wid;
  const float* xr = x + (size_t)t * H_DIM;
  float acc[E_NUM];
#pragma unroll
  for (int e = 0; e < E_NUM; ++e) acc[e] = 0.f;
#pragma unroll
  for (int c = 0; c < H_DIM / 256; ++c) {
    const int h0 = c * 256 + lane * 4;
    f32x4 xv = *(const f32x4*)(xr + h0);
    u16x4 p;
    p.x = f2bf(xv.x); p.y = f2bf(xv.y); p.z = f2bf(xv.z); p.w = f2bf(xv.w);
    *(u16x4*)(xb + (size_t)t * H_DIM + h0) = p;
#pragma unroll
    for (int e = 0; e < E_NUM; ++e) {
      f32x4 gv = *(const f32x4*)(gw + (size_t)e * H_DIM + h0);
      acc[e] += xv.x * gv.x + xv.y * gv.y + xv.z * gv.z + xv.w * gv.w;
    }
  }
#pragma unroll
  for (int e = 0; e < E_NUM; ++e) {
#pragma unroll
    for (int off = 32; off >= 1; off >>= 1) acc[e] += __shfl_xor(acc[e], off, 64);
  }
  if (lane == 0) {
#pragma unroll
    for (int e = 0; e < E_NUM; ++e) logits[(size_t)t * E_NUM + e] = acc[e];
    int i0 = 0;
    float m0 = acc[0];
    for (int e = 1; e < E_NUM; ++e)
      if (acc[e] > m0) { m0 = acc[e]; i0 = e; }
    int i1 = -1;
    float m1 = -3.4e38f;
    for (int e = 0; e < E_NUM; ++e)
      if (e != i0 && acc[e] > m1) { m1 = acc[e]; i1 = e; }
    float ex = expf(m1 - m0);
    float w0 = 1.f / (1.f + ex);
    float w1 = ex * w0;
    tIdx[t * 2] = i0; tIdx[t * 2 + 1] = i1;
    tW[t * 2] = w0;  tW[t * 2 + 1] = w1;
    atomicAdd(&ctrl[i0], 1);
    atomicAdd(&ctrl[i1], 1);
  }
}

// ---------------------------------------------------------------------------
// Plan (parallel): offsets, cursors, flat M-tile map
// ---------------------------------------------------------------------------
__global__ __launch_bounds__(256) void plan_kernel(int* __restrict__ ctrl) {
  __shared__ int cnt[E_NUM], offs[E_NUM + 1], tbase[E_NUM + 1];
  const int t = threadIdx.x;
  if (t < E_NUM) cnt[t] = ctrl[t];
  __syncthreads();
  if (t == 0) {
    int off = 0, mt = 0;
    for (int e = 0; e < E_NUM; ++e) {
      offs[e] = off; tbase[e] = mt;
      ctrl[8 + e] = off;
      ctrl[16 + e] = off;
      off += cnt[e];
      mt += (cnt[e] + BM - 1) / BM;
    }
    offs[E_NUM] = off; tbase[E_NUM] = mt;
    ctrl[24] = mt;
  }
  __syncthreads();
  const int total = tbase[E_NUM];
  for (int i = t; i < total; i += 256) {
    int e = 0;
    while (tbase[e + 1] <= i) ++e;
    ctrl[32 + i] = e;
    ctrl[32 + MAX_MT + i] = offs[e] + (i - tbase[e]) * BM;
  }
}

__global__ __launch_bounds__(256) void scatter_kernel(
    const int* __restrict__ tIdx, const float* __restrict__ tW,
    int* __restrict__ ctrl, int* __restrict__ pairTok,
    float* __restrict__ pairWgt) {
  const int t = blockIdx.x * 256 + threadIdx.x;
  if (t >= T_TOK) return;
#pragma unroll
  for (int j = 0; j < 2; ++j) {
    const int e = tIdx[t * 2 + j];
    const int pos = atomicAdd(&ctrl[16 + e], 1);
    pairTok[pos] = t;
    pairWgt[pos] = tW[t * 2 + j];
  }
}

// ---------------------------------------------------------------------------
// GEMM1: h = silu(x·w1^T) * (x·w3^T)  (bf16 out)
// 2-PHASE FINE INTERLEAVE (m196/m233): each barrier-to-barrier segment has
// {GLD issue || ds_read || MFMA cluster}. P1: A+B1 prefetch + acc1 MFMAs.
// P2: B3 prefetch + acc3 MFMAs + counted vmcnt(6) (never drains newest stage).
// 3 buffers, depth-2. w2-converts fused 1-per-3 (verified).
// ---------------------------------------------------------------------------
template <int BBF>
__global__ __launch_bounds__(256, 2) void gemm1_kernel(
    const float* __restrict__ w1f, const float* __restrict__ w3f,
    const unsigned short* __restrict__ w1b,
    const unsigned short* __restrict__ w3b,
    const unsigned short* __restrict__ xb, const int* __restrict__ ctrl,
    const int* __restrict__ pairTok, unsigned short* __restrict__ hbuf,
    const float* __restrict__ w2f, unsigned short* __restrict__ w2b,
    int nconv) {
  int gid = blockIdx.x;
  const int nconv3 = nconv * 3;
  if (gid < nconv3) {
    if ((gid % 3) == 2) {
      const int cid = gid / 3;
      const long long per = (long long)E_NUM * F_DIM * H_DIM / 8 / NCONV;
      long long i = (long long)cid * per + threadIdx.x;
      const long long end = (long long)(cid + 1) * per;
      for (; i < end; i += 256) {
        f32x4 a = *(const f32x4*)(w2f + i * 8);
        f32x4 b = *(const f32x4*)(w2f + i * 8 + 4);
        *(s16x8*)(w2b + i * 8) = pack8(a, b);
      }
      return;
    }
    gid = gid - (gid + 1) / 3;
  } else {
    gid = gid - nconv;
  }

  const int mtTotal = ctrl[24];
  const int mt = gid >> 5;   // nt-major: same-weight-tile blocks 32 apart
  const int nt = gid & 31;   // -> same XCD -> L2 reuse
  if (mt >= mtTotal) return;
  const int e = ctrl[32 + mt];
  const int mbase = ctrl[32 + MAX_MT + mt];
  int mValid = ctrl[8 + e] + ctrl[e] - mbase;
  if (mValid > BM) mValid = BM;
  const int nbase = nt * BN;

  __shared__ __align__(16) short sA[3][BM * BK];
  __shared__ __align__(16) short sB1[3][BM * BK];
  __shared__ __align__(16) short sB3[3][BM * BK];
  __shared__ int sTok[BM];

  const int tid = threadIdx.x;
  if (tid < BM) sTok[tid] = pairTok[mbase + (tid < mValid ? tid : 0)];
  __syncthreads();

  const int c0 = tid, c1 = tid + 256;
  const int r0 = c0 >> 2, r1 = c1 >> 2;
  const int kg0 = (c0 & 3) ^ ((r0 >> 1) & 3);
  const int kg1 = (c1 & 3) ^ ((r1 >> 1) & 3);

  const unsigned short* srcA0 = xb + (size_t)sTok[r0] * H_DIM + kg0 * 8;
  const unsigned short* srcA1 = xb + (size_t)sTok[r1] * H_DIM + kg1 * 8;
  const size_t wbase = (size_t)e * F_DIM * H_DIM;
  const float *f10, *f11, *f30, *f31;
  const unsigned short *p10, *p11, *p30, *p31;
  if constexpr (BBF) {
    p10 = w1b + wbase + (size_t)(nbase + r0) * H_DIM + kg0 * 8;
    p11 = w1b + wbase + (size_t)(nbase + r1) * H_DIM + kg1 * 8;
    p30 = w3b + wbase + (size_t)(nbase + r0) * H_DIM + kg0 * 8;
    p31 = w3b + wbase + (size_t)(nbase + r1) * H_DIM + kg1 * 8;
  } else {
    f10 = w1f + wbase + (size_t)(nbase + r0) * H_DIM + kg0 * 8;
    f11 = w1f + wbase + (size_t)(nbase + r1) * H_DIM + kg1 * 8;
    f30 = w3f + wbase + (size_t)(nbase + r0) * H_DIM + kg0 * 8;
    f31 = w3f + wbase + (size_t)(nbase + r1) * H_DIM + kg1 * 8;
  }

  f32x4 acc1[4][4], acc3[4][4];
  const f32x4 fz = {0.f, 0.f, 0.f, 0.f};
#pragma unroll
  for (int i = 0; i < 4; ++i)
#pragma unroll
    for (int j = 0; j < 4; ++j) { acc1[i][j] = fz; acc3[i][j] = fz; }

  const int lane = tid & 63, wid = tid >> 6;
  const int wm = (wid >> 1) * 64, wn = (wid & 1) * 64;
  const int rl = lane & 15, kq = lane >> 4;

  int aIdx[4], bIdx[4];
#pragma unroll
  for (int i = 0; i < 4; ++i) {
    const int ra = wm + i * 16 + rl;
    aIdx[i] = ra * BK + ((kq ^ ((ra >> 1) & 3)) * 8);
    const int rb = wn + i * 16 + rl;
    bIdx[i] = rb * BK + ((kq ^ ((rb >> 1) & 3)) * 8);
  }

#define STAGE_AB1(buf, k0)                                                     \
  {                                                                            \
    GLD16(srcA0 + (k0), &sA[buf][c0 * 8]);                                     \
    GLD16(srcA1 + (k0), &sA[buf][c1 * 8]);                                     \
    if constexpr (BBF) {                                                       \
      GLD16(p10 + (k0), &sB1[buf][c0 * 8]);                                    \
      GLD16(p11 + (k0), &sB1[buf][c1 * 8]);                                    \
    } else {                                                                   \
      f32x4 t0 = *(const f32x4*)(f10 + (k0));                                  \
      f32x4 t1 = *(const f32x4*)(f10 + (k0) + 4);                              \
      *(s16x8*)&sB1[buf][c0 * 8] = pack8(t0, t1);                              \
      t0 = *(const f32x4*)(f11 + (k0));                                        \
      t1 = *(const f32x4*)(f11 + (k0) + 4);                                    \
      *(s16x8*)&sB1[buf][c1 * 8] = pack8(t0, t1);                              \
    }                                                                          \
  }
#define STAGE_B3(buf, k0)                                                      \
  {                                                                            \
    if constexpr (BBF) {                                                       \
      GLD16(p30 + (k0), &sB3[buf][c0 * 8]);                                    \
      GLD16(p31 + (k0), &sB3[buf][c1 * 8]);                                    \
    } else {                                                                   \
      f32x4 t0 = *(const f32x4*)(f30 + (k0));                                  \
      f32x4 t1 = *(const f32x4*)(f30 + (k0) + 4);                              \
      *(s16x8*)&sB3[buf][c0 * 8] = pack8(t0, t1);                              \
      t0 = *(const f32x4*)(f31 + (k0));                                        \
      t1 = *(const f32x4*)(f31 + (k0) + 4);                                    \
      *(s16x8*)&sB3[buf][c1 * 8] = pack8(t0, t1);                              \
    }                                                                          \
  }

  // prologue: stage 0,1; retire stage 0; barrier
  STAGE_AB1(0, 0);
  STAGE_B3(0, 0);
  STAGE_AB1(1, BK);
  STAGE_B3(1, BK);
  if constexpr (BBF)
    asm volatile("s_waitcnt vmcnt(6)" ::: "memory");
  else
    asm volatile("s_waitcnt vmcnt(0) lgkmcnt(0)" ::: "memory");
  __builtin_amdgcn_s_barrier();
  asm volatile("" ::: "memory");

  const int NS = H_DIM / BK;  // 64
  int cur = 0;
  for (int s = 0; s < NS; ++s) {
    const bool pf = (s + 2 < NS);
    const int nxt = (cur + 2 >= 3) ? cur - 1 : cur + 2;

    // ---- Phase 1: A+B1 prefetch issue || ds_read af,bf1 || 16 MFMA acc1 ----
    if (pf) STAGE_AB1(nxt, (s + 2) * BK);
    asm volatile("" ::: "memory");
    bf16x8 af[4], bf1[4];
#pragma unroll
    for (int i = 0; i < 4; ++i) {
      af[i] = *(const bf16x8*)&sA[cur][aIdx[i]];
      bf1[i] = *(const bf16x8*)&sB1[cur][bIdx[i]];
    }
    __builtin_amdgcn_s_setprio(1);
#pragma unroll
    for (int mr = 0; mr < 4; ++mr)
#pragma unroll
      for (int nr = 0; nr < 4; ++nr)
        acc1[mr][nr] = __builtin_amdgcn_mfma_f32_16x16x32_bf16(
            af[mr], bf1[nr], acc1[mr][nr], 0, 0, 0);
    __builtin_amdgcn_s_setprio(0);
    asm volatile("" ::: "memory");
    __builtin_amdgcn_s_barrier();
    asm volatile("" ::: "memory");

    // ---- Phase 2: B3 prefetch issue || ds_read bf3 || 16 MFMA acc3 ----
    if (pf) STAGE_B3(nxt, (s + 2) * BK);
    asm volatile("" ::: "memory");
    bf16x8 bf3[4];
#pragma unroll
    for (int i = 0; i < 4; ++i) bf3[i] = *(const bf16x8*)&sB3[cur][bIdx[i]];
    __builtin_amdgcn_s_setprio(1);
#pragma unroll
    for (int mr = 0; mr < 4; ++mr)
#pragma unroll
      for (int nr = 0; nr < 4; ++nr)
        acc3[mr][nr] = __builtin_amdgcn_mfma_f32_16x16x32_bf16(
            af[mr], bf3[nr], acc3[mr][nr], 0, 0, 0);
    __builtin_amdgcn_s_setprio(0);
    asm volatile("" ::: "memory");

    if (s + 1 < NS) {
      if constexpr (BBF) {
        if (pf)
          asm volatile("s_waitcnt vmcnt(6)" ::: "memory");
        else
          asm volatile("s_waitcnt vmcnt(0)" ::: "memory");
      } else {
        asm volatile("s_waitcnt vmcnt(0) lgkmcnt(0)" ::: "memory");
      }
      __builtin_amdgcn_s_barrier();
      asm volatile("" ::: "memory");
    }
    cur = (cur + 1 >= 3) ? 0 : cur + 1;
  }

#pragma unroll
  for (int mr = 0; mr < 4; ++mr) {
#pragma unroll
    for (int j = 0; j < 4; ++j) {
      const int row = wm + mr * 16 + kq * 4 + j;
      if (row < mValid) {
        unsigned short* dst =
            hbuf + (size_t)(mbase + row) * F_DIM + nbase + wn + rl;
#pragma unroll
        for (int nr = 0; nr < 4; ++nr) {
          const float z = acc1[mr][nr][j];
          const float hv = (z / (1.f + expf(-z))) * acc3[mr][nr][j];
          dst[nr * 16] = f2bf(hv);
        }
      }
    }
  }
#undef STAGE_AB1
#undef STAGE_B3
}

// ---------------------------------------------------------------------------
// GEMM2: out[tok] += wgt * (h·w2^T) — 2-phase fine interleave.
// P1: A prefetch + 8 MFMA (nr 0,1). P2: B prefetch + 8 MFMA (nr 2,3) +
// counted vmcnt(4). XCD-clustered bid mapping (round 12).
// ---------------------------------------------------------------------------
template <int BBF>
__global__ __launch_bounds__(256, 2) void gemm2_kernel(
    const float* __restrict__ w2f, const unsigned short* __restrict__ w2b,
    const unsigned short* __restrict__ hbuf, const int* __restrict__ ctrl,
    const int* __restrict__ pairTok, const float* __restrict__ pairWgt,
    float* __restrict__ out) {
  const int mtTotal = ctrl[24];
  const int mt = (blockIdx.x >> 7) * 8 + (blockIdx.x & 7);  // bid%8 = mt%8
  const int nt = (blockIdx.x >> 3) & 15;
  if (mt >= mtTotal) return;
  const int e = ctrl[32 + mt];
  const int mbase = ctrl[32 + MAX_MT + mt];
  int mValid = ctrl[8 + e] + ctrl[e] - mbase;
  if (mValid > BM) mValid = BM;
  const int nbase = nt * BN;

  __shared__ __align__(16) short sA[3][BM * BK];
  __shared__ __align__(16) short sB[3][BM * BK];
  __shared__ int sTok[BM];
  __shared__ float sWgt[BM];

  const int tid = threadIdx.x;
  if (tid < BM) {
    const int p = mbase + (tid < mValid ? tid : 0);
    sTok[tid] = pairTok[p];
    sWgt[tid] = pairWgt[p];
  }
  __syncthreads();

  const int c0 = tid, c1 = tid + 256;
  const int r0 = c0 >> 2, r1 = c1 >> 2;
  const int kg0 = (c0 & 3) ^ ((r0 >> 1) & 3);
  const int kg1 = (c1 & 3) ^ ((r1 >> 1) & 3);

  size_t pa0 = (size_t)(mbase + r0); if (pa0 > MAXPAIR - 1) pa0 = MAXPAIR - 1;
  size_t pa1 = (size_t)(mbase + r1); if (pa1 > MAXPAIR - 1) pa1 = MAXPAIR - 1;
  const unsigned short* srcA0 = hbuf + pa0 * F_DIM + kg0 * 8;
  const unsigned short* srcA1 = hbuf + pa1 * F_DIM + kg1 * 8;
  const size_t wbase = (size_t)e * H_DIM * F_DIM;
  const float *fw0, *fw1;
  const unsigned short *pw0, *pw1;
  if constexpr (BBF) {
    pw0 = w2b + wbase + (size_t)(nbase + r0) * F_DIM + kg0 * 8;
    pw1 = w2b + wbase + (size_t)(nbase + r1) * F_DIM + kg1 * 8;
  } else {
    fw0 = w2f + wbase + (size_t)(nbase + r0) * F_DIM + kg0 * 8;
    fw1 = w2f + wbase + (size_t)(nbase + r1) * F_DIM + kg1 * 8;
  }

  f32x4 acc[4][4];
  const f32x4 fz = {0.f, 0.f, 0.f, 0.f};
#pragma unroll
  for (int i = 0; i < 4; ++i)
#pragma unroll
    for (int j = 0; j < 4; ++j) acc[i][j] = fz;

  const int lane = tid & 63, wid = tid >> 6;
  const int wm = (wid >> 1) * 64, wn = (wid & 1) * 64;
  const int rl = lane & 15, kq = lane >> 4;

  int aIdx[4], bIdx[4];
#pragma unroll
  for (int i = 0; i < 4; ++i) {
    const int ra = wm + i * 16 + rl;
    aIdx[i] = ra * BK + ((kq ^ ((ra >> 1) & 3)) * 8);
    const int rb = wn + i * 16 + rl;
    bIdx[i] = rb * BK + ((kq ^ ((rb >> 1) & 3)) * 8);
  }

#define STAGE_A2(buf, k0)                                                      \
  {                                                                            \
    GLD16(srcA0 + (k0), &sA[buf][c0 * 8]);                                     \
    GLD16(srcA1 + (k0), &sA[buf][c1 * 8]);                                     \
  }
#define STAGE_B2(buf, k0)                                                      \
  {                                                                            \
    if constexpr (BBF) {                                                       \
      GLD16(pw0 + (k0), &sB[buf][c0 * 8]);                                     \
      GLD16(pw1 + (k0), &sB[buf][c1 * 8]);                                     \
    } else {                                                                   \
      f32x4 t0 = *(const f32x4*)(fw0 + (k0));                                  \
      f32x4 t1 = *(const f32x4*)(fw0 + (k0) + 4);                              \
      *(s16x8*)&sB[buf][c0 * 8] = pack8(t0, t1);                               \
      t0 = *(const f32x4*)(fw1 + (k0));                                        \
      t1 = *(const f32x4*)(fw1 + (k0) + 4);                                    \
      *(s16x8*)&sB[buf][c1 * 8] = pack8(t0, t1);                               \
    }                                                                          \
  }

  STAGE_A2(0, 0);
  STAGE_B2(0, 0);
  STAGE_A2(1, BK);
  STAGE_B2(1, BK);
  if constexpr (BBF)
    asm volatile("s_waitcnt vmcnt(4)" ::: "memory");
  else
    asm volatile("s_waitcnt vmcnt(0) lgkmcnt(0)" ::: "memory");
  __builtin_amdgcn_s_barrier();
  asm volatile("" ::: "memory");

  const int NS = F_DIM / BK;  // 128
  int cur = 0;
  for (int s = 0; s < NS; ++s) {
    const bool pf = (s + 2 < NS);
    const int nxt = (cur + 2 >= 3) ? cur - 1 : cur + 2;

    // ---- Phase 1: A prefetch || ds_read af,bf[0..1] || 8 MFMA ----
    if (pf) STAGE_A2(nxt, (s + 2) * BK);
    asm volatile("" ::: "memory");
    bf16x8 af[4], bf[4];
#pragma unroll
    for (int i = 0; i < 4; ++i) af[i] = *(const bf16x8*)&sA[cur][aIdx[i]];
#pragma unroll
    for (int i = 0; i < 2; ++i) bf[i] = *(const bf16x8*)&sB[cur][bIdx[i]];
    __builtin_amdgcn_s_setprio(1);
#pragma unroll
    for (int mr = 0; mr < 4; ++mr)
#pragma unroll
      for (int nr = 0; nr < 2; ++nr)
        acc[mr][nr] = __builtin_amdgcn_mfma_f32_16x16x32_bf16(
            af[mr], bf[nr], acc[mr][nr], 0, 0, 0);
    __builtin_amdgcn_s_setprio(0);
    asm volatile("" ::: "memory");
    __builtin_amdgcn_s_barrier();
    asm volatile("" ::: "memory");

    // ---- Phase 2: B prefetch || ds_read bf[2..3] || 8 MFMA ----
    if (pf) STAGE_B2(nxt, (s + 2) * BK);
    asm volatile("" ::: "memory");
#pragma unroll
    for (int i = 2; i < 4; ++i) bf[i] = *(const bf16x8*)&sB[cur][bIdx[i]];
    __builtin_amdgcn_s_setprio(1);
#pragma unroll
    for (int mr = 0; mr < 4; ++mr)
#pragma unroll
      for (int nr = 2; nr < 4; ++nr)
        acc[mr][nr] = __builtin_amdgcn_mfma_f32_16x16x32_bf16(
            af[mr], bf[nr], acc[mr][nr], 0, 0, 0);
    __builtin_amdgcn_s_setprio(0);
    asm volatile("" ::: "memory");

    if (s + 1 < NS) {
      if constexpr (BBF) {
        if (pf)
          asm volatile("s_waitcnt vmcnt(4)" ::: "memory");
        else
          asm volatile("s_waitcnt vmcnt(0)" ::: "memory");
      } else {
        asm volatile("s_waitcnt vmcnt(0) lgkmcnt(0)" ::: "memory");
      }
      __builtin_amdgcn_s_barrier();
      asm volatile("" ::: "memory");
    }
    cur = (cur + 1 >= 3) ? 0 : cur + 1;
  }

#pragma unroll
  for (int mr = 0; mr < 4; ++mr) {
#pragma unroll
    for (int j = 0; j < 4; ++j) {
      const int row = wm + mr * 16 + kq * 4 + j;
      if (row < mValid) {
        const int tok = sTok[row];
        const float w = sWgt[row];
        float* dst = out + (size_t)tok * H_DIM + nbase + wn + rl;
#pragma unroll
        for (int nr = 0; nr < 4; ++nr)
          unsafeAtomicAdd(dst + nr * 16, w * acc[mr][nr][j]);
      }
    }
  }
#undef STAGE_A2
#undef STAGE_B2
}

// ---------------------------------------------------------------------------
extern "C" void kernel_launch(void* const* d_in, const int* in_sizes, int n_in,
                              void* d_out, int out_size, void* d_ws,
                              size_t ws_size, hipStream_t stream) {
  const float* x  = (const float*)d_in[0];
  const float* gw = (const float*)d_in[1];
  const float* w1 = (const float*)d_in[2];
  const float* w3 = (const float*)d_in[3];
  const float* w2 = (const float*)d_in[4];
  float* out = (float*)d_out;                  // [T, H]
  float* logits = out + (size_t)T_TOK * H_DIM; // [T, E]

  char* ws = (char*)d_ws;
  const size_t HDR = 1u << 20;
  const size_t XB_SZ = (size_t)T_TOK * H_DIM * 2;           // 32 MiB
  const size_t HB_SZ = (size_t)MAXPAIR * F_DIM * 2;         // 128 MiB
  const size_t W_SZ  = (size_t)E_NUM * F_DIM * H_DIM * 2;   // 128 MiB each

  int* ctrl = (int*)(ws);
  int* tIdx = (int*)(ws + 4096);
  float* tW = (float*)(ws + 4096 + 65536);
  int* pairTok = (int*)(ws + 4096 + 131072);
  float* pairWgt = (float*)(ws + 4096 + 196608);
  unsigned short* xb = (unsigned short*)(ws + HDR);
  unsigned short* hbuf = (unsigned short*)(ws + HDR + XB_SZ);
  unsigned short* w1b = (unsigned short*)(ws + HDR + XB_SZ + HB_SZ);
  unsigned short* w3b = w1b + W_SZ / 2;
  unsigned short* w2b = w3b + W_SZ / 2;

  const bool cw13 = ws_size >= HDR + XB_SZ + HB_SZ + 2 * W_SZ;
  const bool cw2  = ws_size >= HDR + XB_SZ + HB_SZ + 3 * W_SZ;

  hipMemsetAsync(ctrl, 0, 4096, stream);
  hipMemsetAsync(out, 0, (size_t)T_TOK * H_DIM * sizeof(float), stream);

  // Router + fused w1/w3 converts (6144 blocks) — or plain router if no ws.
  if (cw13)
    router_conv_kernel<<<6144, 256, 0, stream>>>(
        x, gw, logits, xb, ctrl, tIdx, tW, w1, w1b, w3, w3b, NCONV13);
  else
    router_conv_kernel<<<T_TOK / 4, 256, 0, stream>>>(
        x, gw, logits, xb, ctrl, tIdx, tW, w1, w1b, w3, w3b, 0);

  plan_kernel<<<1, 256, 0, stream>>>(ctrl);
  scatter_kernel<<<T_TOK / 256, 256, 0, stream>>>(tIdx, tW, ctrl, pairTok, pairWgt);

  const int NG = MAX_MT * 32;  // 4352 gemm blocks
  if (cw13) {
    const int nconv = cw2 ? NCONV : 0;
    gemm1_kernel<1><<<NG + nconv, 256, 0, stream>>>(
        w1, w3, w1b, w3b, xb, ctrl, pairTok, hbuf, w2, w2b, nconv);
  } else {
    gemm1_kernel<0><<<NG, 256, 0, stream>>>(
        w1, w3, w1b, w3b, xb, ctrl, pairTok, hbuf, w2, w2b, 0);
  }
  if (cw2)
    gemm2_kernel<1><<<MAX_MT * 16, 256, 0, stream>>>(w2, w2b, hbuf, ctrl,
                                                     pairTok, pairWgt, out);
  else
    gemm2_kernel<0><<<MAX_MT * 16, 256, 0, stream>>>(w2, w2b, hbuf, ctrl,
                                                     pairTok, pairWgt, out);
}

// Round 14
// 1505.439 us; speedup vs baseline: 1.0966x; 1.0966x over previous
//
#include <hip/hip_runtime.h>
#include <math.h>

#define T_TOK 8192
#define H_DIM 2048
#define F_DIM 4096
#define E_NUM 8
#define MAXPAIR (T_TOK * 2)
#define MAX_MT 136
#define MAX_MT2 72
#define BM 128
#define BM1 256
#define BN 128
#define BK 32
#define NCONV 2048   // w2-convert blocks fused into gemm1 dispatch
#define NCONV13 4096 // w1/w3-convert blocks fused into router dispatch

typedef __attribute__((ext_vector_type(4))) float f32x4;
typedef __attribute__((ext_vector_type(8))) short s16x8;
typedef __attribute__((ext_vector_type(8))) __bf16 bf16x8;
typedef __attribute__((ext_vector_type(4))) unsigned short u16x4;

__device__ __forceinline__ unsigned short f2bf(float f) {
  unsigned int u = __float_as_uint(f);
  u += 0x7FFFu + ((u >> 16) & 1u);
  return (unsigned short)(u >> 16);
}

__device__ __forceinline__ s16x8 pack8(f32x4 a, f32x4 b) {
  s16x8 r;
  r[0] = (short)f2bf(a.x); r[1] = (short)f2bf(a.y);
  r[2] = (short)f2bf(a.z); r[3] = (short)f2bf(a.w);
  r[4] = (short)f2bf(b.x); r[5] = (short)f2bf(b.y);
  r[6] = (short)f2bf(b.z); r[7] = (short)f2bf(b.w);
  return r;
}

#define GLD16(gsrc, ldst)                                                      \
  __builtin_amdgcn_global_load_lds(                                            \
      (__attribute__((address_space(1))) void*)(gsrc),                         \
      (__attribute__((address_space(3))) void*)(ldst), 16, 0, 0)

// ---------------------------------------------------------------------------
// Router + fused w1/w3 fp32->bf16 converts (verified round 9)
// ---------------------------------------------------------------------------
__global__ __launch_bounds__(256) void router_conv_kernel(
    const float* __restrict__ x, const float* __restrict__ gw,
    float* __restrict__ logits, unsigned short* __restrict__ xb,
    int* __restrict__ ctrl, int* __restrict__ tIdx, float* __restrict__ tW,
    const float* __restrict__ w1f, unsigned short* __restrict__ w1b,
    const float* __restrict__ w3f, unsigned short* __restrict__ w3b,
    int nconv) {
  int rb = blockIdx.x;  // router block id
  if (nconv) {
    const int bid = blockIdx.x;
    if ((bid % 3) != 2) {
      const int cid = bid - (bid + 1) / 3;           // 0..4095
      const float* src = (cid < 2048) ? w1f : w3f;
      unsigned short* dst = (cid < 2048) ? w1b : w3b;
      const long long base = (long long)(cid & 2047) * 4096;
#pragma unroll
      for (int it = 0; it < 16; ++it) {
        const long long i = base + it * 256 + threadIdx.x;
        f32x4 a = *(const f32x4*)(src + i * 8);
        f32x4 b = *(const f32x4*)(src + i * 8 + 4);
        *(s16x8*)(dst + i * 8) = pack8(a, b);
      }
      return;
    }
    rb = bid / 3;  // 0..2047
  }

  const int wid = threadIdx.x >> 6, lane = threadIdx.x & 63;
  const int t = rb * 4 + wid;
  const float* xr = x + (size_t)t * H_DIM;
  float acc[E_NUM];
#pragma unroll
  for (int e = 0; e < E_NUM; ++e) acc[e] = 0.f;
#pragma unroll
  for (int c = 0; c < H_DIM / 256; ++c) {
    const int h0 = c * 256 + lane * 4;
    f32x4 xv = *(const f32x4*)(xr + h0);
    u16x4 p;
    p.x = f2bf(xv.x); p.y = f2bf(xv.y); p.z = f2bf(xv.z); p.w = f2bf(xv.w);
    *(u16x4*)(xb + (size_t)t * H_DIM + h0) = p;
#pragma unroll
    for (int e = 0; e < E_NUM; ++e) {
      f32x4 gv = *(const f32x4*)(gw + (size_t)e * H_DIM + h0);
      acc[e] += xv.x * gv.x + xv.y * gv.y + xv.z * gv.z + xv.w * gv.w;
    }
  }
#pragma unroll
  for (int e = 0; e < E_NUM; ++e) {
#pragma unroll
    for (int off = 32; off >= 1; off >>= 1) acc[e] += __shfl_xor(acc[e], off, 64);
  }
  if (lane == 0) {
#pragma unroll
    for (int e = 0; e < E_NUM; ++e) logits[(size_t)t * E_NUM + e] = acc[e];
    int i0 = 0;
    float m0 = acc[0];
    for (int e = 1; e < E_NUM; ++e)
      if (acc[e] > m0) { m0 = acc[e]; i0 = e; }
    int i1 = -1;
    float m1 = -3.4e38f;
    for (int e = 0; e < E_NUM; ++e)
      if (e != i0 && acc[e] > m1) { m1 = acc[e]; i1 = e; }
    float ex = expf(m1 - m0);
    float w0 = 1.f / (1.f + ex);
    float w1 = ex * w0;
    tIdx[t * 2] = i0; tIdx[t * 2 + 1] = i1;
    tW[t * 2] = w0;  tW[t * 2 + 1] = w1;
    atomicAdd(&ctrl[i0], 1);
    atomicAdd(&ctrl[i1], 1);
  }
}

// ---------------------------------------------------------------------------
// Plan (parallel): offsets, cursors, TWO flat M-tile maps
// ctrl: [0..7] counts, [8..15] offsets, [16..23] cursors, [24] mtTotal(128),
//       [25] mtTotal2(256), [32..168) e1, [168..304) mbase1,
//       [304..376) e2, [384..456) mbase2
// ---------------------------------------------------------------------------
__global__ __launch_bounds__(256) void plan_kernel(int* __restrict__ ctrl) {
  __shared__ int cnt[E_NUM], offs[E_NUM + 1], tb1[E_NUM + 1], tb2[E_NUM + 1];
  const int t = threadIdx.x;
  if (t < E_NUM) cnt[t] = ctrl[t];
  __syncthreads();
  if (t == 0) {
    int off = 0, mt = 0, mt2 = 0;
    for (int e = 0; e < E_NUM; ++e) {
      offs[e] = off; tb1[e] = mt; tb2[e] = mt2;
      ctrl[8 + e] = off;
      ctrl[16 + e] = off;
      mt += (cnt[e] + BM - 1) / BM;
      mt2 += (cnt[e] + BM1 - 1) / BM1;
      off += cnt[e];
    }
    offs[E_NUM] = off; tb1[E_NUM] = mt; tb2[E_NUM] = mt2;
    ctrl[24] = mt;
    ctrl[25] = mt2;
  }
  __syncthreads();
  for (int i = t; i < tb1[E_NUM]; i += 256) {
    int e = 0;
    while (tb1[e + 1] <= i) ++e;
    ctrl[32 + i] = e;
    ctrl[32 + MAX_MT + i] = offs[e] + (i - tb1[e]) * BM;
  }
  for (int i = t; i < tb2[E_NUM]; i += 256) {
    int e = 0;
    while (tb2[e + 1] <= i) ++e;
    ctrl[304 + i] = e;
    ctrl[384 + i] = offs[e] + (i - tb2[e]) * BM1;
  }
}

__global__ __launch_bounds__(256) void scatter_kernel(
    const int* __restrict__ tIdx, const float* __restrict__ tW,
    int* __restrict__ ctrl, int* __restrict__ pairTok,
    float* __restrict__ pairWgt) {
  const int t = blockIdx.x * 256 + threadIdx.x;
  if (t >= T_TOK) return;
#pragma unroll
  for (int j = 0; j < 2; ++j) {
    const int e = tIdx[t * 2 + j];
    const int pos = atomicAdd(&ctrl[16 + e], 1);
    pairTok[pos] = t;
    pairWgt[pos] = tW[t * 2 + j];
  }
}

// ---------------------------------------------------------------------------
// GEMM1 (8-phase-template geometry): h = silu(x·w1^T)*(x·w3^T), bf16 out.
// 256x128 tile, BK=64, 512 thr (8 waves, 4M x 2N; wave 64x64 dual-stream).
// LDS 129KB: 2 buf x 2 half x {A 256x32, B1 128x32, B3 128x32}, proven
// swizzle per half. Per K-tile: two super-phases, each
// {issue 4 GLD16 of next tile's half || 12 ds_read || 32 MFMA}, separated by
// counted vmcnt(4)+barrier (outstanding queue always [needed:4][newer:4]).
// w2-convert blocks fused 1-per-3 (verified).
// ---------------------------------------------------------------------------
template <int BBF>
__global__ __launch_bounds__(512, 2) void gemm1_kernel(
    const float* __restrict__ w1f, const float* __restrict__ w3f,
    const unsigned short* __restrict__ w1b,
    const unsigned short* __restrict__ w3b,
    const unsigned short* __restrict__ xb, const int* __restrict__ ctrl,
    const int* __restrict__ pairTok, unsigned short* __restrict__ hbuf,
    const float* __restrict__ w2f, unsigned short* __restrict__ w2b,
    int nconv) {
  int gid = blockIdx.x;
  const int nconv3 = nconv * 3;
  if (gid < nconv3) {
    if ((gid % 3) == 2) {
      const int cid = gid / 3;
      const long long per = (long long)E_NUM * F_DIM * H_DIM / 8 / NCONV;
      long long i = (long long)cid * per + threadIdx.x;
      const long long end = (long long)(cid + 1) * per;
      for (; i < end; i += 512) {
        f32x4 a = *(const f32x4*)(w2f + i * 8);
        f32x4 b = *(const f32x4*)(w2f + i * 8 + 4);
        *(s16x8*)(w2b + i * 8) = pack8(a, b);
      }
      return;
    }
    gid = gid - (gid + 1) / 3;
  } else {
    gid = gid - nconv;
  }

  const int mtTotal = ctrl[25];
  const int mt = gid >> 5;   // nt-major: co-resident same-nt blocks share B
  const int nt = gid & 31;   // in one XCD's L2 (bid%8 = f(nt))
  if (mt >= mtTotal) return;
  const int e = ctrl[304 + mt];
  const int mbase = ctrl[384 + mt];
  int mValid = ctrl[8 + e] + ctrl[e] - mbase;
  if (mValid > BM1) mValid = BM1;
  const int nbase = nt * BN;

  __shared__ __align__(16) short sA[2][2][BM1 * 32];   // 64 KB
  __shared__ __align__(16) short sB1[2][2][BN * 32];   // 32 KB
  __shared__ __align__(16) short sB3[2][2][BN * 32];   // 32 KB
  __shared__ int sTok[BM1];

  const int tid = threadIdx.x;
  if (tid < BM1) sTok[tid] = pairTok[mbase + (tid < mValid ? tid : 0)];
  __syncthreads();

  // A: 1024 chunks (row*4 + slot), slot = kg ^ ((row>>1)&3); 2 per thread
  const int cA0 = tid, cA1 = tid + 512;
  const int rA0 = cA0 >> 2, rA1 = cA1 >> 2;
  const int kgA0 = (cA0 & 3) ^ ((rA0 >> 1) & 3);
  const int kgA1 = (cA1 & 3) ^ ((rA1 >> 1) & 3);
  const unsigned short* srcA0 = xb + (size_t)sTok[rA0] * H_DIM + kgA0 * 8;
  const unsigned short* srcA1 = xb + (size_t)sTok[rA1] * H_DIM + kgA1 * 8;
  // B: 512 chunks; 1 per thread
  const int cB = tid;
  const int rB = cB >> 2;
  const int kgB = (cB & 3) ^ ((rB >> 1) & 3);
  const size_t wbase = (size_t)e * F_DIM * H_DIM;
  const float *f1p, *f3p;
  const unsigned short *p1p, *p3p;
  if constexpr (BBF) {
    p1p = w1b + wbase + (size_t)(nbase + rB) * H_DIM + kgB * 8;
    p3p = w3b + wbase + (size_t)(nbase + rB) * H_DIM + kgB * 8;
  } else {
    f1p = w1f + wbase + (size_t)(nbase + rB) * H_DIM + kgB * 8;
    f3p = w3f + wbase + (size_t)(nbase + rB) * H_DIM + kgB * 8;
  }

  f32x4 acc1[4][4], acc3[4][4];
  const f32x4 fz = {0.f, 0.f, 0.f, 0.f};
#pragma unroll
  for (int i = 0; i < 4; ++i)
#pragma unroll
    for (int j = 0; j < 4; ++j) { acc1[i][j] = fz; acc3[i][j] = fz; }

  const int lane = tid & 63, wid = tid >> 6;
  const int wm = (wid >> 1) * 64;  // 0,64,128,192
  const int wn = (wid & 1) * 64;   // 0,64
  const int rl = lane & 15, kq = lane >> 4;

  int aIdx[4], bIdx[4];
#pragma unroll
  for (int i = 0; i < 4; ++i) {
    const int ra = wm + i * 16 + rl;
    aIdx[i] = ra * 32 + ((kq ^ ((ra >> 1) & 3)) * 8);
    const int rb = wn + i * 16 + rl;
    bIdx[i] = rb * 32 + ((kq ^ ((rb >> 1) & 3)) * 8);
  }

#define ST_A(buf, h, koff)                                                     \
  {                                                                            \
    GLD16(srcA0 + (koff), &sA[buf][h][cA0 * 8]);                               \
    GLD16(srcA1 + (koff), &sA[buf][h][cA1 * 8]);                               \
  }
#define ST_B(buf, h, koff)                                                     \
  {                                                                            \
    if constexpr (BBF) {                                                       \
      GLD16(p1p + (koff), &sB1[buf][h][cB * 8]);                               \
      GLD16(p3p + (koff), &sB3[buf][h][cB * 8]);                               \
    } else {                                                                   \
      f32x4 t0 = *(const f32x4*)(f1p + (koff));                                \
      f32x4 t1 = *(const f32x4*)(f1p + (koff) + 4);                            \
      *(s16x8*)&sB1[buf][h][cB * 8] = pack8(t0, t1);                           \
      t0 = *(const f32x4*)(f3p + (koff));                                      \
      t1 = *(const f32x4*)(f3p + (koff) + 4);                                  \
      *(s16x8*)&sB3[buf][h][cB * 8] = pack8(t0, t1);                           \
    }                                                                          \
  }
#define WAITC1(N)                                                              \
  {                                                                            \
    if constexpr (BBF)                                                         \
      asm volatile("s_waitcnt vmcnt(" #N ")" ::: "memory");                    \
    else                                                                       \
      asm volatile("s_waitcnt vmcnt(0) lgkmcnt(0)" ::: "memory");              \
  }

  // prologue: tile 0 both halves (h0 first -> oldest 4 = h0)
  ST_A(0, 0, 0);
  ST_B(0, 0, 0);
  ST_A(0, 1, 32);
  ST_B(0, 1, 32);
  WAITC1(4);
  __builtin_amdgcn_s_barrier();
  asm volatile("" ::: "memory");

  const int NT = H_DIM / 64;  // 32 K-tiles
  for (int t = 0; t < NT; ++t) {
    const int buf = t & 1, nb = buf ^ 1;
    const bool pf = (t + 1 < NT);
    const int kn = (t + 1) * 64;

    // ---- super-phase 0 (half 0): issue next h0 || ds_read || 32 MFMA ----
    if (pf) ST_A(nb, 0, kn);
    asm volatile("" ::: "memory");
    bf16x8 af[4], bf1[4], bf3[4];
#pragma unroll
    for (int i = 0; i < 4; ++i) {
      af[i] = *(const bf16x8*)&sA[buf][0][aIdx[i]];
      bf1[i] = *(const bf16x8*)&sB1[buf][0][bIdx[i]];
    }
    __builtin_amdgcn_s_setprio(1);
#pragma unroll
    for (int mr = 0; mr < 4; ++mr)
#pragma unroll
      for (int nr = 0; nr < 4; ++nr)
        acc1[mr][nr] = __builtin_amdgcn_mfma_f32_16x16x32_bf16(
            af[mr], bf1[nr], acc1[mr][nr], 0, 0, 0);
    __builtin_amdgcn_s_setprio(0);
    if (pf) ST_B(nb, 0, kn);
    asm volatile("" ::: "memory");
#pragma unroll
    for (int i = 0; i < 4; ++i) bf3[i] = *(const bf16x8*)&sB3[buf][0][bIdx[i]];
    __builtin_amdgcn_s_setprio(1);
#pragma unroll
    for (int mr = 0; mr < 4; ++mr)
#pragma unroll
      for (int nr = 0; nr < 4; ++nr)
        acc3[mr][nr] = __builtin_amdgcn_mfma_f32_16x16x32_bf16(
            af[mr], bf3[nr], acc3[mr][nr], 0, 0, 0);
    __builtin_amdgcn_s_setprio(0);
    asm volatile("" ::: "memory");
    // mid sync: retire half1 of tile t (outstanding: [h1(t):4][h0(t+1):4])
    if (pf) { WAITC1(4); } else { WAITC1(0); }
    __builtin_amdgcn_s_barrier();
    asm volatile("" ::: "memory");

    // ---- super-phase 1 (half 1): issue next h1 || ds_read || 32 MFMA ----
    if (pf) ST_A(nb, 1, kn + 32);
    asm volatile("" ::: "memory");
#pragma unroll
    for (int i = 0; i < 4; ++i) {
      af[i] = *(const bf16x8*)&sA[buf][1][aIdx[i]];
      bf1[i] = *(const bf16x8*)&sB1[buf][1][bIdx[i]];
    }
    __builtin_amdgcn_s_setprio(1);
#pragma unroll
    for (int mr = 0; mr < 4; ++mr)
#pragma unroll
      for (int nr = 0; nr < 4; ++nr)
        acc1[mr][nr] = __builtin_amdgcn_mfma_f32_16x16x32_bf16(
            af[mr], bf1[nr], acc1[mr][nr], 0, 0, 0);
    __builtin_amdgcn_s_setprio(0);
    if (pf) ST_B(nb, 1, kn + 32);
    asm volatile("" ::: "memory");
#pragma unroll
    for (int i = 0; i < 4; ++i) bf3[i] = *(const bf16x8*)&sB3[buf][1][bIdx[i]];
    __builtin_amdgcn_s_setprio(1);
#pragma unroll
    for (int mr = 0; mr < 4; ++mr)
#pragma unroll
      for (int nr = 0; nr < 4; ++nr)
        acc3[mr][nr] = __builtin_amdgcn_mfma_f32_16x16x32_bf16(
            af[mr], bf3[nr], acc3[mr][nr], 0, 0, 0);
    __builtin_amdgcn_s_setprio(0);
    asm volatile("" ::: "memory");
    // end sync: retire half0 of tile t+1 (outstanding: [h0(t+1):4][h1(t+1):4])
    if (pf) {
      WAITC1(4);
      __builtin_amdgcn_s_barrier();
      asm volatile("" ::: "memory");
    }
  }

#pragma unroll
  for (int mr = 0; mr < 4; ++mr) {
#pragma unroll
    for (int j = 0; j < 4; ++j) {
      const int row = wm + mr * 16 + kq * 4 + j;
      if (row < mValid) {
        unsigned short* dst =
            hbuf + (size_t)(mbase + row) * F_DIM + nbase + wn + rl;
#pragma unroll
        for (int nr = 0; nr < 4; ++nr) {
          const float z = acc1[mr][nr][j];
          const float hv = (z / (1.f + expf(-z))) * acc3[mr][nr][j];
          dst[nr * 16] = f2bf(hv);
        }
      }
    }
  }
#undef ST_A
#undef ST_B
#undef WAITC1
}

// ---------------------------------------------------------------------------
// GEMM2: out[tok] += wgt * (h·w2^T) — verified round-12 kernel (1-barrier
// counted schedule, XCD-clustered bid mapping), byte-identical.
// ---------------------------------------------------------------------------
template <int BBF>
__global__ __launch_bounds__(256, 2) void gemm2_kernel(
    const float* __restrict__ w2f, const unsigned short* __restrict__ w2b,
    const unsigned short* __restrict__ hbuf, const int* __restrict__ ctrl,
    const int* __restrict__ pairTok, const float* __restrict__ pairWgt,
    float* __restrict__ out) {
  const int mtTotal = ctrl[24];
  const int mt = (blockIdx.x >> 7) * 8 + (blockIdx.x & 7);  // bid%8 = mt%8
  const int nt = (blockIdx.x >> 3) & 15;
  if (mt >= mtTotal) return;
  const int e = ctrl[32 + mt];
  const int mbase = ctrl[32 + MAX_MT + mt];
  int mValid = ctrl[8 + e] + ctrl[e] - mbase;
  if (mValid > BM) mValid = BM;
  const int nbase = nt * BN;

  __shared__ __align__(16) short sA[3][BM * BK];
  __shared__ __align__(16) short sB[3][BM * BK];
  __shared__ int sTok[BM];
  __shared__ float sWgt[BM];

  const int tid = threadIdx.x;
  if (tid < BM) {
    const int p = mbase + (tid < mValid ? tid : 0);
    sTok[tid] = pairTok[p];
    sWgt[tid] = pairWgt[p];
  }
  __syncthreads();

  const int c0 = tid, c1 = tid + 256;
  const int r0 = c0 >> 2, r1 = c1 >> 2;
  const int kg0 = (c0 & 3) ^ ((r0 >> 1) & 3);
  const int kg1 = (c1 & 3) ^ ((r1 >> 1) & 3);

  size_t pa0 = (size_t)(mbase + r0); if (pa0 > MAXPAIR - 1) pa0 = MAXPAIR - 1;
  size_t pa1 = (size_t)(mbase + r1); if (pa1 > MAXPAIR - 1) pa1 = MAXPAIR - 1;
  const unsigned short* srcA0 = hbuf + pa0 * F_DIM + kg0 * 8;
  const unsigned short* srcA1 = hbuf + pa1 * F_DIM + kg1 * 8;
  const size_t wbase = (size_t)e * H_DIM * F_DIM;
  const float *fw0, *fw1;
  const unsigned short *pw0, *pw1;
  if constexpr (BBF) {
    pw0 = w2b + wbase + (size_t)(nbase + r0) * F_DIM + kg0 * 8;
    pw1 = w2b + wbase + (size_t)(nbase + r1) * F_DIM + kg1 * 8;
  } else {
    fw0 = w2f + wbase + (size_t)(nbase + r0) * F_DIM + kg0 * 8;
    fw1 = w2f + wbase + (size_t)(nbase + r1) * F_DIM + kg1 * 8;
  }

  f32x4 acc[4][4];
  const f32x4 fz = {0.f, 0.f, 0.f, 0.f};
#pragma unroll
  for (int i = 0; i < 4; ++i)
#pragma unroll
    for (int j = 0; j < 4; ++j) acc[i][j] = fz;

  const int lane = tid & 63, wid = tid >> 6;
  const int wm = (wid >> 1) * 64, wn = (wid & 1) * 64;
  const int rl = lane & 15, kq = lane >> 4;

  int aIdx[4], bIdx[4];
#pragma unroll
  for (int i = 0; i < 4; ++i) {
    const int ra = wm + i * 16 + rl;
    aIdx[i] = ra * BK + ((kq ^ ((ra >> 1) & 3)) * 8);
    const int rb = wn + i * 16 + rl;
    bIdx[i] = rb * BK + ((kq ^ ((rb >> 1) & 3)) * 8);
  }

#define STAGE2(buf, k0)                                                        \
  {                                                                            \
    GLD16(srcA0 + (k0), &sA[buf][c0 * 8]);                                     \
    GLD16(srcA1 + (k0), &sA[buf][c1 * 8]);                                     \
    if constexpr (BBF) {                                                       \
      GLD16(pw0 + (k0), &sB[buf][c0 * 8]);                                     \
      GLD16(pw1 + (k0), &sB[buf][c1 * 8]);                                     \
    } else {                                                                   \
      f32x4 t0 = *(const f32x4*)(fw0 + (k0));                                  \
      f32x4 t1 = *(const f32x4*)(fw0 + (k0) + 4);                              \
      *(s16x8*)&sB[buf][c0 * 8] = pack8(t0, t1);                               \
      t0 = *(const f32x4*)(fw1 + (k0));                                        \
      t1 = *(const f32x4*)(fw1 + (k0) + 4);                                    \
      *(s16x8*)&sB[buf][c1 * 8] = pack8(t0, t1);                               \
    }                                                                          \
  }

  STAGE2(0, 0);
  STAGE2(1, BK);
  if constexpr (BBF)
    asm volatile("s_waitcnt vmcnt(4)" ::: "memory");
  else
    asm volatile("s_waitcnt vmcnt(0) lgkmcnt(0)" ::: "memory");
  __builtin_amdgcn_s_barrier();
  asm volatile("" ::: "memory");

  const int NS = F_DIM / BK;  // 128
  int cur = 0;
  for (int s = 0; s < NS; ++s) {
    if (s + 2 < NS) {
      const int nxt = (cur + 2 >= 3) ? cur - 1 : cur + 2;
      STAGE2(nxt, (s + 2) * BK);
    }
    asm volatile("" ::: "memory");

    bf16x8 af[4], bf[4];
#pragma unroll
    for (int i = 0; i < 4; ++i) {
      af[i] = *(const bf16x8*)&sA[cur][aIdx[i]];
      bf[i] = *(const bf16x8*)&sB[cur][bIdx[i]];
    }
    __builtin_amdgcn_s_setprio(1);
#pragma unroll
    for (int mr = 0; mr < 4; ++mr)
#pragma unroll
      for (int nr = 0; nr < 4; ++nr)
        acc[mr][nr] = __builtin_amdgcn_mfma_f32_16x16x32_bf16(
            af[mr], bf[nr], acc[mr][nr], 0, 0, 0);
    __builtin_amdgcn_s_setprio(0);
    asm volatile("" ::: "memory");

    if (s + 1 < NS) {
      if constexpr (BBF) {
        if (s + 2 < NS)
          asm volatile("s_waitcnt vmcnt(4)" ::: "memory");
        else
          asm volatile("s_waitcnt vmcnt(0)" ::: "memory");
      } else {
        asm volatile("s_waitcnt vmcnt(0) lgkmcnt(0)" ::: "memory");
      }
      __builtin_amdgcn_s_barrier();
      asm volatile("" ::: "memory");
    }
    cur = (cur + 1 >= 3) ? 0 : cur + 1;
  }

#pragma unroll
  for (int mr = 0; mr < 4; ++mr) {
#pragma unroll
    for (int j = 0; j < 4; ++j) {
      const int row = wm + mr * 16 + kq * 4 + j;
      if (row < mValid) {
        const int tok = sTok[row];
        const float w = sWgt[row];
        float* dst = out + (size_t)tok * H_DIM + nbase + wn + rl;
#pragma unroll
        for (int nr = 0; nr < 4; ++nr)
          unsafeAtomicAdd(dst + nr * 16, w * acc[mr][nr][j]);
      }
    }
  }
#undef STAGE2
}

// ---------------------------------------------------------------------------
extern "C" void kernel_launch(void* const* d_in, const int* in_sizes, int n_in,
                              void* d_out, int out_size, void* d_ws,
                              size_t ws_size, hipStream_t stream) {
  const float* x  = (const float*)d_in[0];
  const float* gw = (const float*)d_in[1];
  const float* w1 = (const float*)d_in[2];
  const float* w3 = (const float*)d_in[3];
  const float* w2 = (const float*)d_in[4];
  float* out = (float*)d_out;                  // [T, H]
  float* logits = out + (size_t)T_TOK * H_DIM; // [T, E]

  char* ws = (char*)d_ws;
  const size_t HDR = 1u << 20;
  const size_t XB_SZ = (size_t)T_TOK * H_DIM * 2;           // 32 MiB
  const size_t HB_SZ = (size_t)MAXPAIR * F_DIM * 2;         // 128 MiB
  const size_t W_SZ  = (size_t)E_NUM * F_DIM * H_DIM * 2;   // 128 MiB each

  int* ctrl = (int*)(ws);
  int* tIdx = (int*)(ws + 4096);
  float* tW = (float*)(ws + 4096 + 65536);
  int* pairTok = (int*)(ws + 4096 + 131072);
  float* pairWgt = (float*)(ws + 4096 + 196608);
  unsigned short* xb = (unsigned short*)(ws + HDR);
  unsigned short* hbuf = (unsigned short*)(ws + HDR + XB_SZ);
  unsigned short* w1b = (unsigned short*)(ws + HDR + XB_SZ + HB_SZ);
  unsigned short* w3b = w1b + W_SZ / 2;
  unsigned short* w2b = w3b + W_SZ / 2;

  const bool cw13 = ws_size >= HDR + XB_SZ + HB_SZ + 2 * W_SZ;
  const bool cw2  = ws_size >= HDR + XB_SZ + HB_SZ + 3 * W_SZ;

  hipMemsetAsync(ctrl, 0, 4096, stream);
  hipMemsetAsync(out, 0, (size_t)T_TOK * H_DIM * sizeof(float), stream);

  // Router + fused w1/w3 converts (6144 blocks) — or plain router if no ws.
  if (cw13)
    router_conv_kernel<<<6144, 256, 0, stream>>>(
        x, gw, logits, xb, ctrl, tIdx, tW, w1, w1b, w3, w3b, NCONV13);
  else
    router_conv_kernel<<<T_TOK / 4, 256, 0, stream>>>(
        x, gw, logits, xb, ctrl, tIdx, tW, w1, w1b, w3, w3b, 0);

  plan_kernel<<<1, 256, 0, stream>>>(ctrl);
  scatter_kernel<<<T_TOK / 256, 256, 0, stream>>>(tIdx, tW, ctrl, pairTok, pairWgt);

  if (cw13) {
    const int nconv = cw2 ? NCONV : 0;
    // grid 6144: gemm gids 0..4095 interleaved with 2048 convert blocks;
    // gemm blocks with mt >= mtTotal2 (<=72) exit immediately.
    gemm1_kernel<1><<<nconv ? 6144 : MAX_MT2 * 32, 512, 0, stream>>>(
        w1, w3, w1b, w3b, xb, ctrl, pairTok, hbuf, w2, w2b, nconv);
  } else {
    gemm1_kernel<0><<<MAX_MT2 * 32, 512, 0, stream>>>(
        w1, w3, w1b, w3b, xb, ctrl, pairTok, hbuf, w2, w2b, 0);
  }
  if (cw2)
    gemm2_kernel<1><<<MAX_MT * 16, 256, 0, stream>>>(w2, w2b, hbuf, ctrl,
                                                     pairTok, pairWgt, out);
  else
    gemm2_kernel<0><<<MAX_MT * 16, 256, 0, stream>>>(w2, w2b, hbuf, ctrl,
                                                     pairTok, pairWgt, out);
}

// Round 15
// 1430.039 us; speedup vs baseline: 1.1544x; 1.0527x over previous
//
#include <hip/hip_runtime.h>
#include <math.h>

#define T_TOK 8192
#define H_DIM 2048
#define F_DIM 4096
#define E_NUM 8
#define MAXPAIR (T_TOK * 2)
#define MAX_MT 136
#define BM 128
#define BN 128
#define BK 32
#define NCONV 2048   // w2-convert blocks fused into gemm1 dispatch
#define NCONV13 4096 // w1/w3-convert blocks fused into router dispatch

typedef __attribute__((ext_vector_type(4))) float f32x4;
typedef __attribute__((ext_vector_type(8))) short s16x8;
typedef __attribute__((ext_vector_type(8))) __bf16 bf16x8;
typedef __attribute__((ext_vector_type(4))) unsigned short u16x4;

__device__ __forceinline__ unsigned short f2bf(float f) {
  unsigned int u = __float_as_uint(f);
  u += 0x7FFFu + ((u >> 16) & 1u);
  return (unsigned short)(u >> 16);
}

__device__ __forceinline__ s16x8 pack8(f32x4 a, f32x4 b) {
  s16x8 r;
  r[0] = (short)f2bf(a.x); r[1] = (short)f2bf(a.y);
  r[2] = (short)f2bf(a.z); r[3] = (short)f2bf(a.w);
  r[4] = (short)f2bf(b.x); r[5] = (short)f2bf(b.y);
  r[6] = (short)f2bf(b.z); r[7] = (short)f2bf(b.w);
  return r;
}

#define GLD16(gsrc, ldst)                                                      \
  __builtin_amdgcn_global_load_lds(                                            \
      (__attribute__((address_space(1))) void*)(gsrc),                         \
      (__attribute__((address_space(3))) void*)(ldst), 16, 0, 0)

// ---------------------------------------------------------------------------
// Router + fused w1/w3 fp32->bf16 converts (verified round 9)
// ---------------------------------------------------------------------------
__global__ __launch_bounds__(256) void router_conv_kernel(
    const float* __restrict__ x, const float* __restrict__ gw,
    float* __restrict__ logits, unsigned short* __restrict__ xb,
    int* __restrict__ ctrl, int* __restrict__ tIdx, float* __restrict__ tW,
    const float* __restrict__ w1f, unsigned short* __restrict__ w1b,
    const float* __restrict__ w3f, unsigned short* __restrict__ w3b,
    int nconv) {
  int rb = blockIdx.x;  // router block id
  if (nconv) {
    const int bid = blockIdx.x;
    if ((bid % 3) != 2) {
      const int cid = bid - (bid + 1) / 3;           // 0..4095
      const float* src = (cid < 2048) ? w1f : w3f;
      unsigned short* dst = (cid < 2048) ? w1b : w3b;
      const long long base = (long long)(cid & 2047) * 4096;
#pragma unroll
      for (int it = 0; it < 16; ++it) {
        const long long i = base + it * 256 + threadIdx.x;
        f32x4 a = *(const f32x4*)(src + i * 8);
        f32x4 b = *(const f32x4*)(src + i * 8 + 4);
        *(s16x8*)(dst + i * 8) = pack8(a, b);
      }
      return;
    }
    rb = bid / 3;  // 0..2047
  }

  const int wid = threadIdx.x >> 6, lane = threadIdx.x & 63;
  const int t = rb * 4 + wid;
  const float* xr = x + (size_t)t * H_DIM;
  float acc[E_NUM];
#pragma unroll
  for (int e = 0; e < E_NUM; ++e) acc[e] = 0.f;
#pragma unroll
  for (int c = 0; c < H_DIM / 256; ++c) {
    const int h0 = c * 256 + lane * 4;
    f32x4 xv = *(const f32x4*)(xr + h0);
    u16x4 p;
    p.x = f2bf(xv.x); p.y = f2bf(xv.y); p.z = f2bf(xv.z); p.w = f2bf(xv.w);
    *(u16x4*)(xb + (size_t)t * H_DIM + h0) = p;
#pragma unroll
    for (int e = 0; e < E_NUM; ++e) {
      f32x4 gv = *(const f32x4*)(gw + (size_t)e * H_DIM + h0);
      acc[e] += xv.x * gv.x + xv.y * gv.y + xv.z * gv.z + xv.w * gv.w;
    }
  }
#pragma unroll
  for (int e = 0; e < E_NUM; ++e) {
#pragma unroll
    for (int off = 32; off >= 1; off >>= 1) acc[e] += __shfl_xor(acc[e], off, 64);
  }
  if (lane == 0) {
#pragma unroll
    for (int e = 0; e < E_NUM; ++e) logits[(size_t)t * E_NUM + e] = acc[e];
    int i0 = 0;
    float m0 = acc[0];
    for (int e = 1; e < E_NUM; ++e)
      if (acc[e] > m0) { m0 = acc[e]; i0 = e; }
    int i1 = -1;
    float m1 = -3.4e38f;
    for (int e = 0; e < E_NUM; ++e)
      if (e != i0 && acc[e] > m1) { m1 = acc[e]; i1 = e; }
    float ex = expf(m1 - m0);
    float w0 = 1.f / (1.f + ex);
    float w1 = ex * w0;
    tIdx[t * 2] = i0; tIdx[t * 2 + 1] = i1;
    tW[t * 2] = w0;  tW[t * 2 + 1] = w1;
    atomicAdd(&ctrl[i0], 1);
    atomicAdd(&ctrl[i1], 1);
  }
}

// ---------------------------------------------------------------------------
// Plan (parallel): offsets, cursors, flat M-tile map
// ---------------------------------------------------------------------------
__global__ __launch_bounds__(256) void plan_kernel(int* __restrict__ ctrl) {
  __shared__ int cnt[E_NUM], offs[E_NUM + 1], tbase[E_NUM + 1];
  const int t = threadIdx.x;
  if (t < E_NUM) cnt[t] = ctrl[t];
  __syncthreads();
  if (t == 0) {
    int off = 0, mt = 0;
    for (int e = 0; e < E_NUM; ++e) {
      offs[e] = off; tbase[e] = mt;
      ctrl[8 + e] = off;
      ctrl[16 + e] = off;
      off += cnt[e];
      mt += (cnt[e] + BM - 1) / BM;
    }
    offs[E_NUM] = off; tbase[E_NUM] = mt;
    ctrl[24] = mt;
  }
  __syncthreads();
  const int total = tbase[E_NUM];
  for (int i = t; i < total; i += 256) {
    int e = 0;
    while (tbase[e + 1] <= i) ++e;
    ctrl[32 + i] = e;
    ctrl[32 + MAX_MT + i] = offs[e] + (i - tbase[e]) * BM;
  }
}

__global__ __launch_bounds__(256) void scatter_kernel(
    const int* __restrict__ tIdx, const float* __restrict__ tW,
    int* __restrict__ ctrl, int* __restrict__ pairTok,
    float* __restrict__ pairWgt) {
  const int t = blockIdx.x * 256 + threadIdx.x;
  if (t >= T_TOK) return;
#pragma unroll
  for (int j = 0; j < 2; ++j) {
    const int e = tIdx[t * 2 + j];
    const int pos = atomicAdd(&ctrl[16 + e], 1);
    pairTok[pos] = t;
    pairWgt[pos] = tW[t * 2 + j];
  }
}

// ---------------------------------------------------------------------------
// GEMM1: h = silu(x·w1^T) * (x·w3^T)  (bf16 out) — verified round-10 schedule
// 3 buffers, 1 barrier/K-step, counted vmcnt(6). w2-converts fused 1-per-3.
// ---------------------------------------------------------------------------
template <int BBF>
__global__ __launch_bounds__(256, 2) void gemm1_kernel(
    const float* __restrict__ w1f, const float* __restrict__ w3f,
    const unsigned short* __restrict__ w1b,
    const unsigned short* __restrict__ w3b,
    const unsigned short* __restrict__ xb, const int* __restrict__ ctrl,
    const int* __restrict__ pairTok, unsigned short* __restrict__ hbuf,
    const float* __restrict__ w2f, unsigned short* __restrict__ w2b,
    int nconv) {
  int gid = blockIdx.x;
  const int nconv3 = nconv * 3;
  if (gid < nconv3) {
    if ((gid % 3) == 2) {
      const int cid = gid / 3;
      const long long per = (long long)E_NUM * F_DIM * H_DIM / 8 / NCONV;
      long long i = (long long)cid * per + threadIdx.x;
      const long long end = (long long)(cid + 1) * per;
      for (; i < end; i += 256) {
        f32x4 a = *(const f32x4*)(w2f + i * 8);
        f32x4 b = *(const f32x4*)(w2f + i * 8 + 4);
        *(s16x8*)(w2b + i * 8) = pack8(a, b);
      }
      return;
    }
    gid = gid - (gid + 1) / 3;
  } else {
    gid = gid - nconv;
  }

  const int mtTotal = ctrl[24];
  const int mt = gid >> 5;   // nt-major: same-weight-tile blocks 32 apart
  const int nt = gid & 31;   // -> same XCD -> L2 reuse
  if (mt >= mtTotal) return;
  const int e = ctrl[32 + mt];
  const int mbase = ctrl[32 + MAX_MT + mt];
  int mValid = ctrl[8 + e] + ctrl[e] - mbase;
  if (mValid > BM) mValid = BM;
  const int nbase = nt * BN;

  __shared__ __align__(16) short sA[3][BM * BK];
  __shared__ __align__(16) short sB1[3][BM * BK];
  __shared__ __align__(16) short sB3[3][BM * BK];
  __shared__ int sTok[BM];

  const int tid = threadIdx.x;
  if (tid < BM) sTok[tid] = pairTok[mbase + (tid < mValid ? tid : 0)];
  __syncthreads();

  const int c0 = tid, c1 = tid + 256;
  const int r0 = c0 >> 2, r1 = c1 >> 2;
  const int kg0 = (c0 & 3) ^ ((r0 >> 1) & 3);
  const int kg1 = (c1 & 3) ^ ((r1 >> 1) & 3);

  const unsigned short* srcA0 = xb + (size_t)sTok[r0] * H_DIM + kg0 * 8;
  const unsigned short* srcA1 = xb + (size_t)sTok[r1] * H_DIM + kg1 * 8;
  const size_t wbase = (size_t)e * F_DIM * H_DIM;
  const float *f10, *f11, *f30, *f31;
  const unsigned short *p10, *p11, *p30, *p31;
  if constexpr (BBF) {
    p10 = w1b + wbase + (size_t)(nbase + r0) * H_DIM + kg0 * 8;
    p11 = w1b + wbase + (size_t)(nbase + r1) * H_DIM + kg1 * 8;
    p30 = w3b + wbase + (size_t)(nbase + r0) * H_DIM + kg0 * 8;
    p31 = w3b + wbase + (size_t)(nbase + r1) * H_DIM + kg1 * 8;
  } else {
    f10 = w1f + wbase + (size_t)(nbase + r0) * H_DIM + kg0 * 8;
    f11 = w1f + wbase + (size_t)(nbase + r1) * H_DIM + kg1 * 8;
    f30 = w3f + wbase + (size_t)(nbase + r0) * H_DIM + kg0 * 8;
    f31 = w3f + wbase + (size_t)(nbase + r1) * H_DIM + kg1 * 8;
  }

  f32x4 acc1[4][4], acc3[4][4];
  const f32x4 fz = {0.f, 0.f, 0.f, 0.f};
#pragma unroll
  for (int i = 0; i < 4; ++i)
#pragma unroll
    for (int j = 0; j < 4; ++j) { acc1[i][j] = fz; acc3[i][j] = fz; }

  const int lane = tid & 63, wid = tid >> 6;
  const int wm = (wid >> 1) * 64, wn = (wid & 1) * 64;
  const int rl = lane & 15, kq = lane >> 4;

  int aIdx[4], bIdx[4];
#pragma unroll
  for (int i = 0; i < 4; ++i) {
    const int ra = wm + i * 16 + rl;
    aIdx[i] = ra * BK + ((kq ^ ((ra >> 1) & 3)) * 8);
    const int rb = wn + i * 16 + rl;
    bIdx[i] = rb * BK + ((kq ^ ((rb >> 1) & 3)) * 8);
  }

#define STAGE1(buf, k0)                                                        \
  {                                                                            \
    GLD16(srcA0 + (k0), &sA[buf][c0 * 8]);                                     \
    GLD16(srcA1 + (k0), &sA[buf][c1 * 8]);                                     \
    if constexpr (BBF) {                                                       \
      GLD16(p10 + (k0), &sB1[buf][c0 * 8]);                                    \
      GLD16(p11 + (k0), &sB1[buf][c1 * 8]);                                    \
      GLD16(p30 + (k0), &sB3[buf][c0 * 8]);                                    \
      GLD16(p31 + (k0), &sB3[buf][c1 * 8]);                                    \
    } else {                                                                   \
      f32x4 t0 = *(const f32x4*)(f10 + (k0));                                  \
      f32x4 t1 = *(const f32x4*)(f10 + (k0) + 4);                              \
      *(s16x8*)&sB1[buf][c0 * 8] = pack8(t0, t1);                              \
      t0 = *(const f32x4*)(f11 + (k0));                                        \
      t1 = *(const f32x4*)(f11 + (k0) + 4);                                    \
      *(s16x8*)&sB1[buf][c1 * 8] = pack8(t0, t1);                              \
      t0 = *(const f32x4*)(f30 + (k0));                                        \
      t1 = *(const f32x4*)(f30 + (k0) + 4);                                    \
      *(s16x8*)&sB3[buf][c0 * 8] = pack8(t0, t1);                              \
      t0 = *(const f32x4*)(f31 + (k0));                                        \
      t1 = *(const f32x4*)(f31 + (k0) + 4);                                    \
      *(s16x8*)&sB3[buf][c1 * 8] = pack8(t0, t1);                              \
    }                                                                          \
  }

  STAGE1(0, 0);
  STAGE1(1, BK);
  if constexpr (BBF)
    asm volatile("s_waitcnt vmcnt(6)" ::: "memory");
  else
    asm volatile("s_waitcnt vmcnt(0) lgkmcnt(0)" ::: "memory");
  __builtin_amdgcn_s_barrier();
  asm volatile("" ::: "memory");

  const int NS = H_DIM / BK;  // 64
  int cur = 0;
  for (int s = 0; s < NS; ++s) {
    if (s + 2 < NS) {
      const int nxt = (cur + 2 >= 3) ? cur - 1 : cur + 2;
      STAGE1(nxt, (s + 2) * BK);
    }
    asm volatile("" ::: "memory");

    bf16x8 af[4], bf1[4], bf3[4];
#pragma unroll
    for (int i = 0; i < 4; ++i) {
      af[i] = *(const bf16x8*)&sA[cur][aIdx[i]];
      bf1[i] = *(const bf16x8*)&sB1[cur][bIdx[i]];
      bf3[i] = *(const bf16x8*)&sB3[cur][bIdx[i]];
    }
    __builtin_amdgcn_s_setprio(1);
#pragma unroll
    for (int mr = 0; mr < 4; ++mr)
#pragma unroll
      for (int nr = 0; nr < 4; ++nr) {
        acc1[mr][nr] = __builtin_amdgcn_mfma_f32_16x16x32_bf16(
            af[mr], bf1[nr], acc1[mr][nr], 0, 0, 0);
        acc3[mr][nr] = __builtin_amdgcn_mfma_f32_16x16x32_bf16(
            af[mr], bf3[nr], acc3[mr][nr], 0, 0, 0);
      }
    __builtin_amdgcn_s_setprio(0);
    asm volatile("" ::: "memory");

    if (s + 1 < NS) {
      if constexpr (BBF) {
        if (s + 2 < NS)
          asm volatile("s_waitcnt vmcnt(6)" ::: "memory");
        else
          asm volatile("s_waitcnt vmcnt(0)" ::: "memory");
      } else {
        asm volatile("s_waitcnt vmcnt(0) lgkmcnt(0)" ::: "memory");
      }
      __builtin_amdgcn_s_barrier();
      asm volatile("" ::: "memory");
    }
    cur = (cur + 1 >= 3) ? 0 : cur + 1;
  }

#pragma unroll
  for (int mr = 0; mr < 4; ++mr) {
#pragma unroll
    for (int j = 0; j < 4; ++j) {
      const int row = wm + mr * 16 + kq * 4 + j;
      if (row < mValid) {
        unsigned short* dst =
            hbuf + (size_t)(mbase + row) * F_DIM + nbase + wn + rl;
#pragma unroll
        for (int nr = 0; nr < 4; ++nr) {
          const float z = acc1[mr][nr][j];
          const float hv = (z / (1.f + expf(-z))) * acc3[mr][nr][j];
          dst[nr * 16] = f2bf(hv);
        }
      }
    }
  }
#undef STAGE1
}

// ---------------------------------------------------------------------------
// GEMM2: out[tok] += wgt * (h·w2^T)  — verified round-12 kernel (1-barrier
// counted schedule, XCD-clustered bid mapping).
// ---------------------------------------------------------------------------
template <int BBF>
__global__ __launch_bounds__(256, 2) void gemm2_kernel(
    const float* __restrict__ w2f, const unsigned short* __restrict__ w2b,
    const unsigned short* __restrict__ hbuf, const int* __restrict__ ctrl,
    const int* __restrict__ pairTok, const float* __restrict__ pairWgt,
    float* __restrict__ out) {
  const int mtTotal = ctrl[24];
  const int mt = (blockIdx.x >> 7) * 8 + (blockIdx.x & 7);  // bid%8 = mt%8
  const int nt = (blockIdx.x >> 3) & 15;
  if (mt >= mtTotal) return;
  const int e = ctrl[32 + mt];
  const int mbase = ctrl[32 + MAX_MT + mt];
  int mValid = ctrl[8 + e] + ctrl[e] - mbase;
  if (mValid > BM) mValid = BM;
  const int nbase = nt * BN;

  __shared__ __align__(16) short sA[3][BM * BK];
  __shared__ __align__(16) short sB[3][BM * BK];
  __shared__ int sTok[BM];
  __shared__ float sWgt[BM];

  const int tid = threadIdx.x;
  if (tid < BM) {
    const int p = mbase + (tid < mValid ? tid : 0);
    sTok[tid] = pairTok[p];
    sWgt[tid] = pairWgt[p];
  }
  __syncthreads();

  const int c0 = tid, c1 = tid + 256;
  const int r0 = c0 >> 2, r1 = c1 >> 2;
  const int kg0 = (c0 & 3) ^ ((r0 >> 1) & 3);
  const int kg1 = (c1 & 3) ^ ((r1 >> 1) & 3);

  size_t pa0 = (size_t)(mbase + r0); if (pa0 > MAXPAIR - 1) pa0 = MAXPAIR - 1;
  size_t pa1 = (size_t)(mbase + r1); if (pa1 > MAXPAIR - 1) pa1 = MAXPAIR - 1;
  const unsigned short* srcA0 = hbuf + pa0 * F_DIM + kg0 * 8;
  const unsigned short* srcA1 = hbuf + pa1 * F_DIM + kg1 * 8;
  const size_t wbase = (size_t)e * H_DIM * F_DIM;
  const float *fw0, *fw1;
  const unsigned short *pw0, *pw1;
  if constexpr (BBF) {
    pw0 = w2b + wbase + (size_t)(nbase + r0) * F_DIM + kg0 * 8;
    pw1 = w2b + wbase + (size_t)(nbase + r1) * F_DIM + kg1 * 8;
  } else {
    fw0 = w2f + wbase + (size_t)(nbase + r0) * F_DIM + kg0 * 8;
    fw1 = w2f + wbase + (size_t)(nbase + r1) * F_DIM + kg1 * 8;
  }

  f32x4 acc[4][4];
  const f32x4 fz = {0.f, 0.f, 0.f, 0.f};
#pragma unroll
  for (int i = 0; i < 4; ++i)
#pragma unroll
    for (int j = 0; j < 4; ++j) acc[i][j] = fz;

  const int lane = tid & 63, wid = tid >> 6;
  const int wm = (wid >> 1) * 64, wn = (wid & 1) * 64;
  const int rl = lane & 15, kq = lane >> 4;

  int aIdx[4], bIdx[4];
#pragma unroll
  for (int i = 0; i < 4; ++i) {
    const int ra = wm + i * 16 + rl;
    aIdx[i] = ra * BK + ((kq ^ ((ra >> 1) & 3)) * 8);
    const int rb = wn + i * 16 + rl;
    bIdx[i] = rb * BK + ((kq ^ ((rb >> 1) & 3)) * 8);
  }

#define STAGE2(buf, k0)                                                        \
  {                                                                            \
    GLD16(srcA0 + (k0), &sA[buf][c0 * 8]);                                     \
    GLD16(srcA1 + (k0), &sA[buf][c1 * 8]);                                     \
    if constexpr (BBF) {                                                       \
      GLD16(pw0 + (k0), &sB[buf][c0 * 8]);                                     \
      GLD16(pw1 + (k0), &sB[buf][c1 * 8]);                                     \
    } else {                                                                   \
      f32x4 t0 = *(const f32x4*)(fw0 + (k0));                                  \
      f32x4 t1 = *(const f32x4*)(fw0 + (k0) + 4);                              \
      *(s16x8*)&sB[buf][c0 * 8] = pack8(t0, t1);                               \
      t0 = *(const f32x4*)(fw1 + (k0));                                        \
      t1 = *(const f32x4*)(fw1 + (k0) + 4);                                    \
      *(s16x8*)&sB[buf][c1 * 8] = pack8(t0, t1);                               \
    }                                                                          \
  }

  STAGE2(0, 0);
  STAGE2(1, BK);
  if constexpr (BBF)
    asm volatile("s_waitcnt vmcnt(4)" ::: "memory");
  else
    asm volatile("s_waitcnt vmcnt(0) lgkmcnt(0)" ::: "memory");
  __builtin_amdgcn_s_barrier();
  asm volatile("" ::: "memory");

  const int NS = F_DIM / BK;  // 128
  int cur = 0;
  for (int s = 0; s < NS; ++s) {
    if (s + 2 < NS) {
      const int nxt = (cur + 2 >= 3) ? cur - 1 : cur + 2;
      STAGE2(nxt, (s + 2) * BK);
    }
    asm volatile("" ::: "memory");

    bf16x8 af[4], bf[4];
#pragma unroll
    for (int i = 0; i < 4; ++i) {
      af[i] = *(const bf16x8*)&sA[cur][aIdx[i]];
      bf[i] = *(const bf16x8*)&sB[cur][bIdx[i]];
    }
    __builtin_amdgcn_s_setprio(1);
#pragma unroll
    for (int mr = 0; mr < 4; ++mr)
#pragma unroll
      for (int nr = 0; nr < 4; ++nr)
        acc[mr][nr] = __builtin_amdgcn_mfma_f32_16x16x32_bf16(
            af[mr], bf[nr], acc[mr][nr], 0, 0, 0);
    __builtin_amdgcn_s_setprio(0);
    asm volatile("" ::: "memory");

    if (s + 1 < NS) {
      if constexpr (BBF) {
        if (s + 2 < NS)
          asm volatile("s_waitcnt vmcnt(4)" ::: "memory");
        else
          asm volatile("s_waitcnt vmcnt(0)" ::: "memory");
      } else {
        asm volatile("s_waitcnt vmcnt(0) lgkmcnt(0)" ::: "memory");
      }
      __builtin_amdgcn_s_barrier();
      asm volatile("" ::: "memory");
    }
    cur = (cur + 1 >= 3) ? 0 : cur + 1;
  }

#pragma unroll
  for (int mr = 0; mr < 4; ++mr) {
#pragma unroll
    for (int j = 0; j < 4; ++j) {
      const int row = wm + mr * 16 + kq * 4 + j;
      if (row < mValid) {
        const int tok = sTok[row];
        const float w = sWgt[row];
        float* dst = out + (size_t)tok * H_DIM + nbase + wn + rl;
#pragma unroll
        for (int nr = 0; nr < 4; ++nr)
          unsafeAtomicAdd(dst + nr * 16, w * acc[mr][nr][j]);
      }
    }
  }
#undef STAGE2
}

// ---------------------------------------------------------------------------
extern "C" void kernel_launch(void* const* d_in, const int* in_sizes, int n_in,
                              void* d_out, int out_size, void* d_ws,
                              size_t ws_size, hipStream_t stream) {
  const float* x  = (const float*)d_in[0];
  const float* gw = (const float*)d_in[1];
  const float* w1 = (const float*)d_in[2];
  const float* w3 = (const float*)d_in[3];
  const float* w2 = (const float*)d_in[4];
  float* out = (float*)d_out;                  // [T, H]
  float* logits = out + (size_t)T_TOK * H_DIM; // [T, E]

  char* ws = (char*)d_ws;
  const size_t HDR = 1u << 20;
  const size_t XB_SZ = (size_t)T_TOK * H_DIM * 2;           // 32 MiB
  const size_t HB_SZ = (size_t)MAXPAIR * F_DIM * 2;         // 128 MiB
  const size_t W_SZ  = (size_t)E_NUM * F_DIM * H_DIM * 2;   // 128 MiB each

  int* ctrl = (int*)(ws);
  int* tIdx = (int*)(ws + 4096);
  float* tW = (float*)(ws + 4096 + 65536);
  int* pairTok = (int*)(ws + 4096 + 131072);
  float* pairWgt = (float*)(ws + 4096 + 196608);
  unsigned short* xb = (unsigned short*)(ws + HDR);
  unsigned short* hbuf = (unsigned short*)(ws + HDR + XB_SZ);
  unsigned short* w1b = (unsigned short*)(ws + HDR + XB_SZ + HB_SZ);
  unsigned short* w3b = w1b + W_SZ / 2;
  unsigned short* w2b = w3b + W_SZ / 2;

  const bool cw13 = ws_size >= HDR + XB_SZ + HB_SZ + 2 * W_SZ;
  const bool cw2  = ws_size >= HDR + XB_SZ + HB_SZ + 3 * W_SZ;

  hipMemsetAsync(ctrl, 0, 4096, stream);
  hipMemsetAsync(out, 0, (size_t)T_TOK * H_DIM * sizeof(float), stream);

  // Router + fused w1/w3 converts (6144 blocks) — or plain router if no ws.
  if (cw13)
    router_conv_kernel<<<6144, 256, 0, stream>>>(
        x, gw, logits, xb, ctrl, tIdx, tW, w1, w1b, w3, w3b, NCONV13);
  else
    router_conv_kernel<<<T_TOK / 4, 256, 0, stream>>>(
        x, gw, logits, xb, ctrl, tIdx, tW, w1, w1b, w3, w3b, 0);

  plan_kernel<<<1, 256, 0, stream>>>(ctrl);
  scatter_kernel<<<T_TOK / 256, 256, 0, stream>>>(tIdx, tW, ctrl, pairTok, pairWgt);

  const int NG = MAX_MT * 32;  // 4352 gemm blocks
  if (cw13) {
    const int nconv = cw2 ? NCONV : 0;
    gemm1_kernel<1><<<NG + nconv, 256, 0, stream>>>(
        w1, w3, w1b, w3b, xb, ctrl, pairTok, hbuf, w2, w2b, nconv);
  } else {
    gemm1_kernel<0><<<NG, 256, 0, stream>>>(
        w1, w3, w1b, w3b, xb, ctrl, pairTok, hbuf, w2, w2b, 0);
  }
  if (cw2)
    gemm2_kernel<1><<<MAX_MT * 16, 256, 0, stream>>>(w2, w2b, hbuf, ctrl,
                                                     pairTok, pairWgt, out);
  else
    gemm2_kernel<0><<<MAX_MT * 16, 256, 0, stream>>>(w2, w2b, hbuf, ctrl,
                                                     pairTok, pairWgt, out);
}